// Round 1
// baseline (1001.544 us; speedup 1.0000x reference)
//
#include <hip/hip_runtime.h>
#include <math.h>

// Problem constants
#define RM 13056      // 256*17*3 rows of flat x
#define KD 512        // feature dim
#define NE 2048       // codebook entries
#define NELEM 6684672.0  // 256*51*512 elements for the mean

// dist kernel tiling
#define BM 64
#define BN 128
#define BK 32
#define NH 1024       // N half per block (N split 2-way over blockIdx.y)
#define NT 8          // NH / BN tiles per block
#define SXLD 68       // padded LDS stride for x (64+4): conflict-free, 16B-aligned
#define SELD 132      // padded LDS stride for e (128+4)

// ---------------------------------------------------------------------------
// K0: per-codeword squared norms  EN[n] = sum_k E[n][k]^2
__global__ __launch_bounds__(256) void k_emb_norms(const float* __restrict__ E,
                                                   float* __restrict__ EN) {
  int n = blockIdx.x * 4 + (threadIdx.x >> 6);
  int lane = threadIdx.x & 63;
  const float* e = E + (size_t)n * KD;
  float s = 0.f;
#pragma unroll
  for (int j = 0; j < 8; ++j) { float v = e[lane + 64 * j]; s += v * v; }
#pragma unroll
  for (int off = 32; off; off >>= 1) s += __shfl_down(s, off);
  if (lane == 0) EN[n] = s;
}

// ---------------------------------------------------------------------------
// K1: fused distance GEMM + per-row top-4 selection over one N-half.
// grid (RM/BM, 2), block 256. Each thread computes a 4x8 register tile.
__global__ __launch_bounds__(256) void k_dist(const float* __restrict__ X,
                                              const float* __restrict__ E,
                                              const float* __restrict__ EN,
                                              int* __restrict__ cand) {
  const int tid = threadIdx.x;
  const int tx = tid & 15, ty = tid >> 4;
  const int rowBase = blockIdx.x * BM;
  const int half = blockIdx.y;
  const int colHalfBase = half * NH;

  __shared__ float sEN[NH];
  union U {
    struct { float sX[BK][SXLD]; float sE[BK][SELD]; } s;  // compute phase
    struct { float cd[BM][65]; int ci[BM][65]; } m;        // merge phase
  };
  __shared__ U u;

  // stage this half's eNorms (1024 floats, 1 float4/thread)
  ((float4*)sEN)[tid] = ((const float4*)(EN + colHalfBase))[tid];

  float td[4][4]; int ti[4][4];
#pragma unroll
  for (int r = 0; r < 4; ++r)
#pragma unroll
    for (int s = 0; s < 4; ++s) { td[r][s] = 3.4e38f; ti[r][s] = 0x7fffffff; }

  const int q = tid & 3;          // float4 slot within a row
  const int xrow = tid >> 2;      // 0..63 (coalesced global reads)

  for (int t = 0; t < NT; ++t) {
    const int colBase = colHalfBase + t * BN;
    float acc[4][8];
#pragma unroll
    for (int r = 0; r < 4; ++r)
#pragma unroll
      for (int c = 0; c < 8; ++c) acc[r][c] = 0.f;

    for (int kt = 0; kt < KD / BK; ++kt) {
      const int kBase = kt * BK;
      __syncthreads();  // protect LDS vs previous chunk's reads
      // stage X chunk (64 rows x 32 k), transposed to sX[k][row]
#pragma unroll
      for (int p = 0; p < 2; ++p) {
        int f4 = q + 4 * p;
        float4 v = *(const float4*)(X + (size_t)(rowBase + xrow) * KD + kBase + 4 * f4);
        u.s.sX[4 * f4 + 0][xrow] = v.x;
        u.s.sX[4 * f4 + 1][xrow] = v.y;
        u.s.sX[4 * f4 + 2][xrow] = v.z;
        u.s.sX[4 * f4 + 3][xrow] = v.w;
      }
      // stage E chunk (128 cols x 32 k), transposed to sE[k][col]
#pragma unroll
      for (int p = 0; p < 4; ++p) {
        int col = (tid >> 2) + 64 * (p & 1);
        int f4 = q + 4 * (p >> 1);
        float4 v = *(const float4*)(E + (size_t)(colBase + col) * KD + kBase + 4 * f4);
        u.s.sE[4 * f4 + 0][col] = v.x;
        u.s.sE[4 * f4 + 1][col] = v.y;
        u.s.sE[4 * f4 + 2][col] = v.z;
        u.s.sE[4 * f4 + 3][col] = v.w;
      }
      __syncthreads();
#pragma unroll
      for (int k = 0; k < BK; ++k) {
        float4 xv = *(const float4*)&u.s.sX[k][4 * ty];
        float4 ea = *(const float4*)&u.s.sE[k][4 * tx];
        float4 eb = *(const float4*)&u.s.sE[k][64 + 4 * tx];
        float xs[4] = {xv.x, xv.y, xv.z, xv.w};
        float es[8] = {ea.x, ea.y, ea.z, ea.w, eb.x, eb.y, eb.z, eb.w};
#pragma unroll
        for (int r = 0; r < 4; ++r)
#pragma unroll
          for (int c = 0; c < 8; ++c) acc[r][c] += xs[r] * es[c];
      }
    }
    // top-4 insert (cols visited in ascending index order; strict < keeps
    // the lower index on ties, matching lax.top_k tie-breaking)
#pragma unroll
    for (int r = 0; r < 4; ++r) {
#pragma unroll
      for (int h = 0; h < 2; ++h) {
#pragma unroll
        for (int j = 0; j < 4; ++j) {
          const int cl = h * 64 + 4 * tx + j;
          const float s = sEN[t * BN + cl] - 2.0f * acc[r][4 * h + j];
          const int cg = colBase + cl;
          if (s < td[r][3]) {
            if (s < td[r][2]) {
              td[r][3] = td[r][2]; ti[r][3] = ti[r][2];
              if (s < td[r][1]) {
                td[r][2] = td[r][1]; ti[r][2] = ti[r][1];
                if (s < td[r][0]) {
                  td[r][1] = td[r][0]; ti[r][1] = ti[r][0];
                  td[r][0] = s; ti[r][0] = cg;
                } else { td[r][1] = s; ti[r][1] = cg; }
              } else { td[r][2] = s; ti[r][2] = cg; }
            } else { td[r][3] = s; ti[r][3] = cg; }
          }
        }
      }
    }
  }

  // merge the 16 per-thread top-4 lists of each row -> per-row top-4
  __syncthreads();
#pragma unroll
  for (int r = 0; r < 4; ++r)
#pragma unroll
    for (int s = 0; s < 4; ++s) {
      u.m.cd[4 * ty + r][4 * tx + s] = td[r][s];
      u.m.ci[4 * ty + r][4 * tx + s] = ti[r][s];
    }
  __syncthreads();
  if (tid < BM) {
    float bd[4] = {3.4e38f, 3.4e38f, 3.4e38f, 3.4e38f};
    int bi[4] = {0x7fffffff, 0x7fffffff, 0x7fffffff, 0x7fffffff};
    for (int qq = 0; qq < 64; ++qq) {
      float s = u.m.cd[tid][qq];
      int c = u.m.ci[tid][qq];
      if (s < bd[3] || (s == bd[3] && c < bi[3])) {
        if (s < bd[2] || (s == bd[2] && c < bi[2])) {
          bd[3] = bd[2]; bi[3] = bi[2];
          if (s < bd[1] || (s == bd[1] && c < bi[1])) {
            bd[2] = bd[1]; bi[2] = bi[1];
            if (s < bd[0] || (s == bd[0] && c < bi[0])) {
              bd[1] = bd[0]; bi[1] = bi[0]; bd[0] = s; bi[0] = c;
            } else { bd[1] = s; bi[1] = c; }
          } else { bd[2] = s; bi[2] = c; }
        } else { bd[3] = s; bi[3] = c; }
      }
    }
    int* dst = cand + (size_t)(rowBase + tid) * 8 + half * 4;
    dst[0] = bi[0]; dst[1] = bi[1]; dst[2] = bi[2]; dst[3] = bi[3];
  }
}

// ---------------------------------------------------------------------------
// K2: fp64 refinement of the 8 candidates/row, gather of nearest codeword,
// and exact per-row SSE for nearest (S1) and third (S3).
__global__ __launch_bounds__(256) void k_refine(const float* __restrict__ X,
                                                const float* __restrict__ E,
                                                const int* __restrict__ cand,
                                                float* __restrict__ outF,
                                                double* __restrict__ rowS) {
  const int row = blockIdx.x;
  const int tid = threadIdx.x;
  __shared__ int sc[8];
  __shared__ double sp[8][4];
  __shared__ int sBest;
  if (tid < 8) sc[tid] = cand[(size_t)row * 8 + tid];
  __syncthreads();
  const float x0 = X[(size_t)row * KD + tid];
  const float x1 = X[(size_t)row * KD + tid + 256];
  double a[8];
#pragma unroll
  for (int c = 0; c < 8; ++c) {
    const float* e = E + (size_t)sc[c] * KD;
    double d0 = (double)e[tid] - (double)x0;
    double d1 = (double)e[tid + 256] - (double)x1;
    a[c] = d0 * d0 + d1 * d1;
  }
#pragma unroll
  for (int c = 0; c < 8; ++c)
#pragma unroll
    for (int off = 32; off; off >>= 1) a[c] += __shfl_down(a[c], off);
  const int w = tid >> 6, lane = tid & 63;
  if (lane == 0) {
#pragma unroll
    for (int c = 0; c < 8; ++c) sp[c][w] = a[c];
  }
  __syncthreads();
  if (tid == 0) {
    double d[8]; int id[8];
#pragma unroll
    for (int c = 0; c < 8; ++c) {
      d[c] = sp[c][0] + sp[c][1] + sp[c][2] + sp[c][3];
      id[c] = sc[c];
    }
    // full sort of 8 by (distance, index) lexicographic
    for (int i = 0; i < 8; ++i)
      for (int j = i + 1; j < 8; ++j)
        if (d[j] < d[i] || (d[j] == d[i] && id[j] < id[i])) {
          double dt = d[i]; d[i] = d[j]; d[j] = dt;
          int it = id[i]; id[i] = id[j]; id[j] = it;
        }
    rowS[2 * row] = d[0];      // SSE to nearest
    rowS[2 * row + 1] = d[2];  // SSE to third
    sBest = id[0];
  }
  __syncthreads();
  const float* e1 = E + (size_t)sBest * KD;
  outF[(size_t)row * KD + tid] = e1[tid];
  outF[(size_t)row * KD + tid + 256] = e1[tid + 256];
}

// ---------------------------------------------------------------------------
// K3: deterministic fp64 reduction over rows -> cp_score, k_loss
__global__ __launch_bounds__(256) void k_finalize(const double* __restrict__ rowS,
                                                  float* __restrict__ out) {
  const int tid = threadIdx.x;
  double a1 = 0.0, a3 = 0.0;
  for (int r = tid; r < RM; r += 256) { a1 += rowS[2 * r]; a3 += rowS[2 * r + 1]; }
#pragma unroll
  for (int off = 32; off; off >>= 1) {
    a1 += __shfl_down(a1, off);
    a3 += __shfl_down(a3, off);
  }
  __shared__ double s1[4], s3[4];
  const int w = tid >> 6, lane = tid & 63;
  if (lane == 0) { s1[w] = a1; s3[w] = a3; }
  __syncthreads();
  if (tid == 0) {
    double S1 = s1[0] + s1[1] + s1[2] + s1[3];
    double S3 = s3[0] + s3[1] + s3[2] + s3[3];
    out[0] = (float)(1.0 - sqrt(S1 / S3));   // cp_score
    out[1] = (float)(0.25 * S1 / NELEM);     // k_loss
  }
}

// ---------------------------------------------------------------------------
extern "C" void kernel_launch(void* const* d_in, const int* in_sizes, int n_in,
                              void* d_out, int out_size, void* d_ws, size_t ws_size,
                              hipStream_t stream) {
  const float* IP = (const float*)d_in[0];   // (256,51,512) fp32
  const float* EMB = (const float*)d_in[1];  // (2048,512) fp32
  float* out = (float*)d_out;                // [cp_score, k_loss, feature_EMA...]

  char* ws = (char*)d_ws;
  float* EN = (float*)(ws + 16);                              // 2048 floats
  int* cand = (int*)(ws + 16 + NE * 4);                       // RM*8 ints
  double* rowS = (double*)(ws + 16 + NE * 4 + (size_t)RM * 8 * 4);  // RM*2 doubles

  hipLaunchKernelGGL(k_emb_norms, dim3(NE / 4), dim3(256), 0, stream, EMB, EN);
  hipLaunchKernelGGL(k_dist, dim3(RM / BM, 2), dim3(256), 0, stream, IP, EMB, EN, cand);
  hipLaunchKernelGGL(k_refine, dim3(RM), dim3(256), 0, stream, IP, EMB, cand, out + 2, rowS);
  hipLaunchKernelGGL(k_finalize, dim3(1), dim3(256), 0, stream, rowS, out);
}

// Round 2
// 895.232 us; speedup vs baseline: 1.1188x; 1.1188x over previous
//
#include <hip/hip_runtime.h>
#include <math.h>

// Problem constants
#define RM 13056         // 256*17*3 rows of flat x
#define KD 512           // feature dim
#define NE 2048          // codebook entries
#define NELEM 6684672.0  // 256*51*512 elements for the mean

// dist kernel tiling
#define BM 128
#define BN 128
#define BK 32
#define SLD 36           // LDS row stride in words (32 + 4 pad, 144B = 16B-aligned)
#define NBLK (NE / BN)   // 16 n-blocks

__device__ __forceinline__ bool dless(float d1, int i1, float d2, int i2) {
  return d1 < d2 || (d1 == d2 && i1 < i2);
}

// ---------------------------------------------------------------------------
// K0: per-codeword squared norms  EN[n] = sum_k E[n][k]^2
__global__ __launch_bounds__(256) void k_emb_norms(const float* __restrict__ E,
                                                   float* __restrict__ EN) {
  int n = blockIdx.x * 4 + (threadIdx.x >> 6);
  int lane = threadIdx.x & 63;
  const float* e = E + (size_t)n * KD;
  float s = 0.f;
#pragma unroll
  for (int j = 0; j < 8; ++j) { float v = e[lane + 64 * j]; s += v * v; }
#pragma unroll
  for (int off = 32; off; off >>= 1) s += __shfl_down(s, off);
  if (lane == 0) EN[n] = s;
}

// ---------------------------------------------------------------------------
// K1: 128x128 distance tile + per-row top-4 within this n-block.
// grid (102,16), block 256. Thread tile 8x8: rows ty+16r, cols tx+16c.
// Bank math: sX read = 4 unique rows/wave, consecutive ty -> +36 words = +4
// banks -> disjoint 16-bank span (conflict-free). sE read = banks 4*tx mod 32
// -> exactly 2-way (free, m136). Staging = ds_write_b128, no transpose.
__global__ __launch_bounds__(256, 3) void k_dist(const float* __restrict__ X,
                                                 const float* __restrict__ E,
                                                 const float* __restrict__ EN,
                                                 float2* __restrict__ cand) {
  __shared__ float sX[BM][SLD];
  __shared__ float sE[BN][SLD];
  __shared__ float sEN[BN];

  const int tid = threadIdx.x;
  const int tx = tid & 15, ty = tid >> 4;
  const int rowBase = blockIdx.x * BM;
  const int colBase = blockIdx.y * BN;

  if (tid < BN) sEN[tid] = EN[colBase + tid];

  const int srow = tid >> 1;          // 0..127
  const int soff = (tid & 1) << 4;    // 0 or 16 floats
  const float* gX = X + (size_t)(rowBase + srow) * KD + soff;
  const float* gE = E + (size_t)(colBase + srow) * KD + soff;

  float acc[8][8];
#pragma unroll
  for (int r = 0; r < 8; ++r)
#pragma unroll
    for (int c = 0; c < 8; ++c) acc[r][c] = 0.f;

  for (int kt = 0; kt < KD / BK; ++kt) {
    const int kb = kt * BK;
    float4 ax[4], bx[4];
#pragma unroll
    for (int j = 0; j < 4; ++j) ax[j] = *(const float4*)(gX + kb + 4 * j);
#pragma unroll
    for (int j = 0; j < 4; ++j) bx[j] = *(const float4*)(gE + kb + 4 * j);
    __syncthreads();  // protect previous iteration's readers
#pragma unroll
    for (int j = 0; j < 4; ++j) *(float4*)&sX[srow][soff + 4 * j] = ax[j];
#pragma unroll
    for (int j = 0; j < 4; ++j) *(float4*)&sE[srow][soff + 4 * j] = bx[j];
    __syncthreads();
#pragma unroll
    for (int kq = 0; kq < 8; ++kq) {
      float4 xv[8];
#pragma unroll
      for (int r = 0; r < 8; ++r) xv[r] = *(const float4*)&sX[ty + 16 * r][4 * kq];
#pragma unroll
      for (int c = 0; c < 8; ++c) {
        float4 ev = *(const float4*)&sE[tx + 16 * c][4 * kq];
#pragma unroll
        for (int r = 0; r < 8; ++r) {
          acc[r][c] += xv[r].x * ev.x;
          acc[r][c] += xv[r].y * ev.y;
          acc[r][c] += xv[r].z * ev.z;
          acc[r][c] += xv[r].w * ev.w;
        }
      }
    }
  }

  // epilogue: per-row top-4 over this block's 128 cols
  float en[8];
#pragma unroll
  for (int c = 0; c < 8; ++c) en[c] = sEN[tx + 16 * c];

#pragma unroll
  for (int r = 0; r < 8; ++r) {
    float a0 = 3.4e38f, a1 = 3.4e38f, a2 = 3.4e38f, a3 = 3.4e38f;
    int i0 = 0x7fffffff, i1 = i0, i2 = i0, i3 = i0;
#pragma unroll
    for (int c = 0; c < 8; ++c) {
      float d = en[c] - 2.0f * acc[r][c];
      int ix = colBase + tx + 16 * c;
      // ascending idx + strict < keeps the lower index on ties
      if (d < a3) {
        if (d < a2) { a3 = a2; i3 = i2;
          if (d < a1) { a2 = a1; i2 = i1;
            if (d < a0) { a1 = a0; i1 = i0; a0 = d; i0 = ix; }
            else { a1 = d; i1 = ix; } }
          else { a2 = d; i2 = ix; } }
        else { a3 = d; i3 = ix; }
      }
    }
    // butterfly merge of sorted top-4 lists across the 16 tx lanes
#pragma unroll
    for (int off = 1; off < 16; off <<= 1) {
      float b0 = __shfl_xor(a0, off, 16), b1 = __shfl_xor(a1, off, 16);
      float b2 = __shfl_xor(a2, off, 16), b3 = __shfl_xor(a3, off, 16);
      int j0 = __shfl_xor(i0, off, 16), j1 = __shfl_xor(i1, off, 16);
      int j2 = __shfl_xor(i2, off, 16), j3 = __shfl_xor(i3, off, 16);
      // bitonic merge lower half: a asc + b reversed; keep mins
      if (dless(b3, j3, a0, i0)) { a0 = b3; i0 = j3; }
      if (dless(b2, j2, a1, i1)) { a1 = b2; i1 = j2; }
      if (dless(b1, j1, a2, i2)) { a2 = b1; i2 = j1; }
      if (dless(b0, j0, a3, i3)) { a3 = b0; i3 = j0; }
      // sort the (bitonic) lower half: CE dist 2, then dist 1
      if (dless(a2, i2, a0, i0)) { float t = a0; a0 = a2; a2 = t; int u = i0; i0 = i2; i2 = u; }
      if (dless(a3, i3, a1, i1)) { float t = a1; a1 = a3; a3 = t; int u = i1; i1 = i3; i3 = u; }
      if (dless(a1, i1, a0, i0)) { float t = a0; a0 = a1; a1 = t; int u = i0; i0 = i1; i1 = u; }
      if (dless(a3, i3, a2, i2)) { float t = a2; a2 = a3; a3 = t; int u = i2; i2 = i3; i3 = u; }
    }
    if (tx == 0) {
      float2* dst = cand + (size_t)(rowBase + ty + 16 * r) * (NBLK * 4) + blockIdx.y * 4;
      dst[0] = make_float2(a0, __int_as_float(i0));
      dst[1] = make_float2(a1, __int_as_float(i1));
      dst[2] = make_float2(a2, __int_as_float(i2));
      dst[3] = make_float2(a3, __int_as_float(i3));
    }
  }
}

// ---------------------------------------------------------------------------
// K1b: merge 64 candidates/row -> global top-8 indices. One wave per row,
// full 64-lane bitonic sort by (dist, idx); idx values are globally unique
// per row so the order is a strict total order.
__global__ __launch_bounds__(256) void k_merge(const float2* __restrict__ cand,
                                               int* __restrict__ top8) {
  const int lane = threadIdx.x & 63;
  const int row = blockIdx.x * 4 + (threadIdx.x >> 6);
  float2 e = cand[(size_t)row * 64 + lane];
  float d = e.x;
  int ix = __float_as_int(e.y);
#pragma unroll
  for (int k = 2; k <= 64; k <<= 1) {
#pragma unroll
    for (int j = k >> 1; j > 0; j >>= 1) {
      float od = __shfl_xor(d, j, 64);
      int oi = __shfl_xor(ix, j, 64);
      bool dirUp = (lane & k) == 0;
      bool lower = (lane & j) == 0;
      bool pl = dless(od, oi, d, ix);
      bool take = (dirUp == lower) ? pl : !pl;
      if (take) { d = od; ix = oi; }
    }
  }
  if (lane < 8) top8[(size_t)row * 8 + lane] = ix;
}

// ---------------------------------------------------------------------------
// K2: fp64 refinement of the 8 candidates/row, gather of nearest codeword,
// and exact per-row SSE for nearest (S1) and third (S3).
__global__ __launch_bounds__(256) void k_refine(const float* __restrict__ X,
                                                const float* __restrict__ E,
                                                const int* __restrict__ top8,
                                                float* __restrict__ outF,
                                                double* __restrict__ rowS) {
  const int row = blockIdx.x;
  const int tid = threadIdx.x;
  __shared__ int sc[8];
  __shared__ double sp[8][4];
  __shared__ int sBest;
  if (tid < 8) sc[tid] = top8[(size_t)row * 8 + tid];
  __syncthreads();
  const float x0 = X[(size_t)row * KD + tid];
  const float x1 = X[(size_t)row * KD + tid + 256];
  double a[8];
#pragma unroll
  for (int c = 0; c < 8; ++c) {
    const float* e = E + (size_t)sc[c] * KD;
    double d0 = (double)e[tid] - (double)x0;
    double d1 = (double)e[tid + 256] - (double)x1;
    a[c] = d0 * d0 + d1 * d1;
  }
#pragma unroll
  for (int c = 0; c < 8; ++c)
#pragma unroll
    for (int off = 32; off; off >>= 1) a[c] += __shfl_down(a[c], off);
  const int w = tid >> 6, lane = tid & 63;
  if (lane == 0) {
#pragma unroll
    for (int c = 0; c < 8; ++c) sp[c][w] = a[c];
  }
  __syncthreads();
  if (tid == 0) {
    double d[8]; int id[8];
#pragma unroll
    for (int c = 0; c < 8; ++c) {
      d[c] = sp[c][0] + sp[c][1] + sp[c][2] + sp[c][3];
      id[c] = sc[c];
    }
    for (int i = 0; i < 8; ++i)
      for (int j = i + 1; j < 8; ++j)
        if (d[j] < d[i] || (d[j] == d[i] && id[j] < id[i])) {
          double dt = d[i]; d[i] = d[j]; d[j] = dt;
          int it = id[i]; id[i] = id[j]; id[j] = it;
        }
    rowS[2 * row] = d[0];      // SSE to nearest
    rowS[2 * row + 1] = d[2];  // SSE to third
    sBest = id[0];
  }
  __syncthreads();
  const float* e1 = E + (size_t)sBest * KD;
  outF[(size_t)row * KD + tid] = e1[tid];
  outF[(size_t)row * KD + tid + 256] = e1[tid + 256];
}

// ---------------------------------------------------------------------------
// K3: deterministic fp64 reduction over rows -> cp_score, k_loss
__global__ __launch_bounds__(256) void k_finalize(const double* __restrict__ rowS,
                                                  float* __restrict__ out) {
  const int tid = threadIdx.x;
  double a1 = 0.0, a3 = 0.0;
  for (int r = tid; r < RM; r += 256) { a1 += rowS[2 * r]; a3 += rowS[2 * r + 1]; }
#pragma unroll
  for (int off = 32; off; off >>= 1) {
    a1 += __shfl_down(a1, off);
    a3 += __shfl_down(a3, off);
  }
  __shared__ double s1[4], s3[4];
  const int w = tid >> 6, lane = tid & 63;
  if (lane == 0) { s1[w] = a1; s3[w] = a3; }
  __syncthreads();
  if (tid == 0) {
    double S1 = s1[0] + s1[1] + s1[2] + s1[3];
    double S3 = s3[0] + s3[1] + s3[2] + s3[3];
    out[0] = (float)(1.0 - sqrt(S1 / S3));   // cp_score
    out[1] = (float)(0.25 * S1 / NELEM);     // k_loss
  }
}

// ---------------------------------------------------------------------------
extern "C" void kernel_launch(void* const* d_in, const int* in_sizes, int n_in,
                              void* d_out, int out_size, void* d_ws, size_t ws_size,
                              hipStream_t stream) {
  const float* IP = (const float*)d_in[0];   // (256,51,512) fp32
  const float* EMB = (const float*)d_in[1];  // (2048,512) fp32
  float* out = (float*)d_out;                // [cp_score, k_loss, feature_EMA...]

  // d_out tail doubles as candidate scratch (fully overwritten by k_refine):
  // 13056 rows x 64 (dist,idx) float2 = 6.68 MB <= out capacity 26.7 MB.
  float2* cand = (float2*)(out + 2);

  char* ws = (char*)d_ws;
  float* EN = (float*)(ws + 16);                               // 2048 floats
  int* top8 = (int*)(ws + 16 + NE * 4);                        // RM*8 ints
  double* rowS = (double*)(ws + 16 + NE * 4 + (size_t)RM * 8 * 4);  // RM*2 doubles

  hipLaunchKernelGGL(k_emb_norms, dim3(NE / 4), dim3(256), 0, stream, EMB, EN);
  hipLaunchKernelGGL(k_dist, dim3(RM / BM, NBLK), dim3(256), 0, stream, IP, EMB, EN, cand);
  hipLaunchKernelGGL(k_merge, dim3(RM / 4), dim3(256), 0, stream, cand, top8);
  hipLaunchKernelGGL(k_refine, dim3(RM), dim3(256), 0, stream, IP, EMB, top8, out + 2, rowS);
  hipLaunchKernelGGL(k_finalize, dim3(1), dim3(256), 0, stream, rowS, out);
}

// Round 3
// 548.008 us; speedup vs baseline: 1.8276x; 1.6336x over previous
//
#include <hip/hip_runtime.h>
#include <math.h>

// Problem constants
#define RM 13056         // 256*17*3 rows of flat x
#define KD 512           // feature dim
#define NE 2048          // codebook entries
#define NELEM 6684672.0  // 256*51*512 elements for the mean

// dist kernel tiling
#define BM 128
#define BN 128
#define BK 32
#define NBLK (NE / BN)   // 16 n-blocks

__device__ __forceinline__ bool dless(float d1, int i1, float d2, int i2) {
  return d1 < d2 || (d1 == d2 && i1 < i2);
}

// async global->LDS, 16B per lane; lds base must be wave-uniform (m104)
__device__ __forceinline__ void dma16(const float* g, float* l) {
  __builtin_amdgcn_global_load_lds((const __attribute__((address_space(1))) void*)g,
                                   (__attribute__((address_space(3))) void*)l, 16, 0, 0);
}

// ---------------------------------------------------------------------------
// K0: per-codeword squared norms  EN[n] = sum_k E[n][k]^2
__global__ __launch_bounds__(256) void k_emb_norms(const float* __restrict__ E,
                                                   float* __restrict__ EN) {
  int n = blockIdx.x * 4 + (threadIdx.x >> 6);
  int lane = threadIdx.x & 63;
  const float* e = E + (size_t)n * KD;
  float s = 0.f;
#pragma unroll
  for (int j = 0; j < 8; ++j) { float v = e[lane + 64 * j]; s += v * v; }
#pragma unroll
  for (int off = 32; off; off >>= 1) s += __shfl_down(s, off);
  if (lane == 0) EN[n] = s;
}

// ---------------------------------------------------------------------------
// K1: 128x128 distance tile + per-row top-4 within this n-block.
// grid (102,16), block 256, thread tile 8x8 (rows ty+16r, cols tx+16c).
// Staging via global_load_lds (no VGPR round trip, conflict-free contiguous
// LDS writes). Unpadded LDS rows of 8 float4-chunks, XOR-swizzled:
// chunk position c' holds global chunk kq = c' ^ (row&7).
// Read banks: X -> 4 distinct chunk-quads/wave (16-lane broadcast each,
// conflict-free); E -> 8 quads x 2-way (free, m136).
__global__ __launch_bounds__(256) void k_dist(const float* __restrict__ X,
                                              const float* __restrict__ E,
                                              const float* __restrict__ EN,
                                              float2* __restrict__ cand) {
  __shared__ float sX[BM * BK];
  __shared__ float sE[BN * BK];
  __shared__ float sEN[BN];

  const int tid = threadIdx.x;
  const int tx = tid & 15, ty = tid >> 4;
  const int w = tid >> 6;              // wave id (uniform per wave)
  const int rowBase = blockIdx.x * BM;
  const int colBase = blockIdx.y * BN;

  if (tid < BN) sEN[tid] = EN[colBase + tid];

  // per-lane DMA source mapping: chunk id q -> (row, swizzled kq)
  int drow[4], dkq[4];
#pragma unroll
  for (int i = 0; i < 4; ++i) {
    int q = i * 256 + tid;             // 0..1023 chunk id
    drow[i] = q >> 3;
    dkq[i] = (q & 7) ^ (drow[i] & 7);
  }

  float acc[8][8];
#pragma unroll
  for (int r = 0; r < 8; ++r)
#pragma unroll
    for (int c = 0; c < 8; ++c) acc[r][c] = 0.f;

  const int xsw = ty & 7;              // read-side swizzle keys
  const int esw = tx & 7;

  for (int kt = 0; kt < KD / BK; ++kt) {
    const int kb = kt * BK;
    __syncthreads();  // previous tile's readers done
#pragma unroll
    for (int i = 0; i < 4; ++i) {
      float* ldst = sX + (i * 256 + w * 64) * 4;   // wave-uniform base
      dma16(X + (size_t)(rowBase + drow[i]) * KD + kb + 4 * dkq[i], ldst);
    }
#pragma unroll
    for (int i = 0; i < 4; ++i) {
      float* ldst = sE + (i * 256 + w * 64) * 4;
      dma16(E + (size_t)(colBase + drow[i]) * KD + kb + 4 * dkq[i], ldst);
    }
    __syncthreads();  // vmcnt drained by compiler before barrier
#pragma unroll
    for (int kq = 0; kq < 8; ++kq) {
      float4 xv[8];
#pragma unroll
      for (int r = 0; r < 8; ++r)
        xv[r] = *(const float4*)&sX[((ty + 16 * r) * 8 + (kq ^ xsw)) * 4];
#pragma unroll
      for (int c = 0; c < 8; ++c) {
        float4 ev = *(const float4*)&sE[((tx + 16 * c) * 8 + (kq ^ esw)) * 4];
#pragma unroll
        for (int r = 0; r < 8; ++r) {
          acc[r][c] += xv[r].x * ev.x;
          acc[r][c] += xv[r].y * ev.y;
          acc[r][c] += xv[r].z * ev.z;
          acc[r][c] += xv[r].w * ev.w;
        }
      }
    }
  }

  // epilogue: per-row top-4 over this block's 128 cols
  float en[8];
#pragma unroll
  for (int c = 0; c < 8; ++c) en[c] = sEN[tx + 16 * c];

#pragma unroll
  for (int r = 0; r < 8; ++r) {
    float a0 = 3.4e38f, a1 = 3.4e38f, a2 = 3.4e38f, a3 = 3.4e38f;
    int i0 = 0x7fffffff, i1 = i0, i2 = i0, i3 = i0;
#pragma unroll
    for (int c = 0; c < 8; ++c) {
      float d = en[c] - 2.0f * acc[r][c];
      int ix = colBase + tx + 16 * c;
      // ascending idx + strict < keeps the lower index on ties
      if (d < a3) {
        if (d < a2) { a3 = a2; i3 = i2;
          if (d < a1) { a2 = a1; i2 = i1;
            if (d < a0) { a1 = a0; i1 = i0; a0 = d; i0 = ix; }
            else { a1 = d; i1 = ix; } }
          else { a2 = d; i2 = ix; } }
        else { a3 = d; i3 = ix; }
      }
    }
    // butterfly merge of sorted top-4 lists across the 16 tx lanes
#pragma unroll
    for (int off = 1; off < 16; off <<= 1) {
      float b0 = __shfl_xor(a0, off, 16), b1 = __shfl_xor(a1, off, 16);
      float b2 = __shfl_xor(a2, off, 16), b3 = __shfl_xor(a3, off, 16);
      int j0 = __shfl_xor(i0, off, 16), j1 = __shfl_xor(i1, off, 16);
      int j2 = __shfl_xor(i2, off, 16), j3 = __shfl_xor(i3, off, 16);
      // bitonic merge lower half: a asc + b reversed; keep mins
      if (dless(b3, j3, a0, i0)) { a0 = b3; i0 = j3; }
      if (dless(b2, j2, a1, i1)) { a1 = b2; i1 = j2; }
      if (dless(b1, j1, a2, i2)) { a2 = b1; i2 = j1; }
      if (dless(b0, j0, a3, i3)) { a3 = b0; i3 = j0; }
      // sort the (bitonic) lower half
      if (dless(a2, i2, a0, i0)) { float t = a0; a0 = a2; a2 = t; int u = i0; i0 = i2; i2 = u; }
      if (dless(a3, i3, a1, i1)) { float t = a1; a1 = a3; a3 = t; int u = i1; i1 = i3; i3 = u; }
      if (dless(a1, i1, a0, i0)) { float t = a0; a0 = a1; a1 = t; int u = i0; i0 = i1; i1 = u; }
      if (dless(a3, i3, a2, i2)) { float t = a2; a2 = a3; a3 = t; int u = i2; i2 = i3; i3 = u; }
    }
    if (tx == 0) {
      float2* dst = cand + (size_t)(rowBase + ty + 16 * r) * (NBLK * 4) + blockIdx.y * 4;
      dst[0] = make_float2(a0, __int_as_float(i0));
      dst[1] = make_float2(a1, __int_as_float(i1));
      dst[2] = make_float2(a2, __int_as_float(i2));
      dst[3] = make_float2(a3, __int_as_float(i3));
    }
  }
}

// ---------------------------------------------------------------------------
// K1b: merge 64 candidates/row -> global top-8 indices. One wave per row,
// 64-lane bitonic sort by (dist, idx); idx unique per row -> total order.
__global__ __launch_bounds__(256) void k_merge(const float2* __restrict__ cand,
                                               int* __restrict__ top8) {
  const int lane = threadIdx.x & 63;
  const int row = blockIdx.x * 4 + (threadIdx.x >> 6);
  float2 e = cand[(size_t)row * 64 + lane];
  float d = e.x;
  int ix = __float_as_int(e.y);
#pragma unroll
  for (int k = 2; k <= 64; k <<= 1) {
#pragma unroll
    for (int j = k >> 1; j > 0; j >>= 1) {
      float od = __shfl_xor(d, j, 64);
      int oi = __shfl_xor(ix, j, 64);
      bool dirUp = (lane & k) == 0;
      bool lower = (lane & j) == 0;
      bool pl = dless(od, oi, d, ix);
      bool take = (dirUp == lower) ? pl : !pl;
      if (take) { d = od; ix = oi; }
    }
  }
  if (lane < 8) top8[(size_t)row * 8 + lane] = ix;
}

// ---------------------------------------------------------------------------
// K2: fp64 refinement of the 8 candidates/row, gather of nearest codeword,
// and exact per-row SSE for nearest (S1) and third (S3).
__global__ __launch_bounds__(256) void k_refine(const float* __restrict__ X,
                                                const float* __restrict__ E,
                                                const int* __restrict__ top8,
                                                float* __restrict__ outF,
                                                double* __restrict__ rowS) {
  const int row = blockIdx.x;
  const int tid = threadIdx.x;
  __shared__ int sc[8];
  __shared__ double sp[8][4];
  __shared__ int sBest;
  if (tid < 8) sc[tid] = top8[(size_t)row * 8 + tid];
  __syncthreads();
  const float x0 = X[(size_t)row * KD + tid];
  const float x1 = X[(size_t)row * KD + tid + 256];
  double a[8];
#pragma unroll
  for (int c = 0; c < 8; ++c) {
    const float* e = E + (size_t)sc[c] * KD;
    double d0 = (double)e[tid] - (double)x0;
    double d1 = (double)e[tid + 256] - (double)x1;
    a[c] = d0 * d0 + d1 * d1;
  }
#pragma unroll
  for (int c = 0; c < 8; ++c)
#pragma unroll
    for (int off = 32; off; off >>= 1) a[c] += __shfl_down(a[c], off);
  const int w = tid >> 6, lane = tid & 63;
  if (lane == 0) {
#pragma unroll
    for (int c = 0; c < 8; ++c) sp[c][w] = a[c];
  }
  __syncthreads();
  if (tid == 0) {
    double d[8]; int id[8];
#pragma unroll
    for (int c = 0; c < 8; ++c) {
      d[c] = sp[c][0] + sp[c][1] + sp[c][2] + sp[c][3];
      id[c] = sc[c];
    }
    for (int i = 0; i < 8; ++i)
      for (int j = i + 1; j < 8; ++j)
        if (d[j] < d[i] || (d[j] == d[i] && id[j] < id[i])) {
          double dt = d[i]; d[i] = d[j]; d[j] = dt;
          int it = id[i]; id[i] = id[j]; id[j] = it;
        }
    rowS[2 * row] = d[0];      // SSE to nearest
    rowS[2 * row + 1] = d[2];  // SSE to third
    sBest = id[0];
  }
  __syncthreads();
  const float* e1 = E + (size_t)sBest * KD;
  outF[(size_t)row * KD + tid] = e1[tid];
  outF[(size_t)row * KD + tid + 256] = e1[tid + 256];
}

// ---------------------------------------------------------------------------
// K3: deterministic fp64 reduction over rows -> cp_score, k_loss
__global__ __launch_bounds__(256) void k_finalize(const double* __restrict__ rowS,
                                                  float* __restrict__ out) {
  const int tid = threadIdx.x;
  double a1 = 0.0, a3 = 0.0;
  for (int r = tid; r < RM; r += 256) { a1 += rowS[2 * r]; a3 += rowS[2 * r + 1]; }
#pragma unroll
  for (int off = 32; off; off >>= 1) {
    a1 += __shfl_down(a1, off);
    a3 += __shfl_down(a3, off);
  }
  __shared__ double s1[4], s3[4];
  const int w = tid >> 6, lane = tid & 63;
  if (lane == 0) { s1[w] = a1; s3[w] = a3; }
  __syncthreads();
  if (tid == 0) {
    double S1 = s1[0] + s1[1] + s1[2] + s1[3];
    double S3 = s3[0] + s3[1] + s3[2] + s3[3];
    out[0] = (float)(1.0 - sqrt(S1 / S3));   // cp_score
    out[1] = (float)(0.25 * S1 / NELEM);     // k_loss
  }
}

// ---------------------------------------------------------------------------
extern "C" void kernel_launch(void* const* d_in, const int* in_sizes, int n_in,
                              void* d_out, int out_size, void* d_ws, size_t ws_size,
                              hipStream_t stream) {
  const float* IP = (const float*)d_in[0];   // (256,51,512) fp32
  const float* EMB = (const float*)d_in[1];  // (2048,512) fp32
  float* out = (float*)d_out;                // [cp_score, k_loss, feature_EMA...]

  // d_out tail doubles as candidate scratch (fully overwritten by k_refine):
  // 13056 rows x 64 (dist,idx) float2 = 6.68 MB <= out capacity 26.7 MB.
  float2* cand = (float2*)(out + 2);

  char* ws = (char*)d_ws;
  float* EN = (float*)(ws + 16);                               // 2048 floats
  int* top8 = (int*)(ws + 16 + NE * 4);                        // RM*8 ints
  double* rowS = (double*)(ws + 16 + NE * 4 + (size_t)RM * 8 * 4);  // RM*2 doubles

  hipLaunchKernelGGL(k_emb_norms, dim3(NE / 4), dim3(256), 0, stream, EMB, EN);
  hipLaunchKernelGGL(k_dist, dim3(RM / BM, NBLK), dim3(256), 0, stream, IP, EMB, EN, cand);
  hipLaunchKernelGGL(k_merge, dim3(RM / 4), dim3(256), 0, stream, cand, top8);
  hipLaunchKernelGGL(k_refine, dim3(RM), dim3(256), 0, stream, IP, EMB, top8, out + 2, rowS);
  hipLaunchKernelGGL(k_finalize, dim3(1), dim3(256), 0, stream, rowS, out);
}

// Round 4
// 339.184 us; speedup vs baseline: 2.9528x; 1.6157x over previous
//
#include <hip/hip_runtime.h>
#include <hip/hip_bf16.h>
#include <math.h>

// Problem constants
#define RM 13056         // 256*17*3 rows of flat x
#define KD 512           // feature dim
#define NE 2048          // codebook entries
#define NELEM 6684672.0  // 256*51*512 elements for the mean

// dist kernel tiling
#define BM 128
#define BN 128
#define BK 32
#define NBLK (NE / BN)   // 16 n-blocks

typedef __attribute__((ext_vector_type(8))) short bf16x8;
typedef __attribute__((ext_vector_type(4))) float f32x4;

__device__ __forceinline__ bool dless(float d1, int i1, float d2, int i2) {
  return d1 < d2 || (d1 == d2 && i1 < i2);
}

// async global->LDS, 16B per lane; lds base wave-uniform, dst = base+lane*16 (m104)
__device__ __forceinline__ void dma16(const void* g, void* l) {
  __builtin_amdgcn_global_load_lds((const __attribute__((address_space(1))) void*)g,
                                   (__attribute__((address_space(3))) void*)l, 16, 0, 0);
}

// ---------------------------------------------------------------------------
// K_pre: split fp32 -> bf16 hi + bf16 residual lo (vectorized x4)
__global__ __launch_bounds__(256) void k_split(const float* __restrict__ src,
                                               unsigned short* __restrict__ hi,
                                               unsigned short* __restrict__ lo,
                                               int n4) {
  int i = blockIdx.x * 256 + threadIdx.x;
  if (i >= n4) return;
  float4 v = ((const float4*)src)[i];
  float f[4] = {v.x, v.y, v.z, v.w};
  unsigned short hh[4], ll[4];
#pragma unroll
  for (int j = 0; j < 4; ++j) {
    __hip_bfloat16 b = __float2bfloat16(f[j]);          // RNE hi
    float bf = __bfloat162float(b);
    __hip_bfloat16 c = __float2bfloat16(f[j] - bf);     // residual lo
    hh[j] = *(unsigned short*)&b;
    ll[j] = *(unsigned short*)&c;
  }
  ((ushort4*)hi)[i] = make_ushort4(hh[0], hh[1], hh[2], hh[3]);
  ((ushort4*)lo)[i] = make_ushort4(ll[0], ll[1], ll[2], ll[3]);
}

// ---------------------------------------------------------------------------
// K0: per-codeword squared norms  EN[n] = sum_k E[n][k]^2 (fp32, as ref)
__global__ __launch_bounds__(256) void k_emb_norms(const float* __restrict__ E,
                                                   float* __restrict__ EN) {
  int n = blockIdx.x * 4 + (threadIdx.x >> 6);
  int lane = threadIdx.x & 63;
  const float* e = E + (size_t)n * KD;
  float s = 0.f;
#pragma unroll
  for (int j = 0; j < 8; ++j) { float v = e[lane + 64 * j]; s += v * v; }
#pragma unroll
  for (int off = 32; off; off >>= 1) s += __shfl_down(s, off);
  if (lane == 0) EN[n] = s;
}

// ---------------------------------------------------------------------------
// LDS chunk layout: row of 32 bf16 = 4 chunks of 8; chunk q stored at slot
// q ^ ((row>>1)&3). Frag reads land on all 8 16B-slots at 2-way (free, m136);
// DMA writes are wave-contiguous (conflict-free).
__device__ __forceinline__ int chidx(int row, int q) {
  return (row * 4 + (q ^ ((row >> 1) & 3))) * 8;  // ushort element offset
}

// K1: split-bf16 MFMA distance tile + per-row top-4 within this n-block.
// grid (102,16), block 256 = 4 waves; wave w owns rows [w*32,w*32+32) x 128 cols.
// Per kt: 48 MFMA (2 mt x 8 ct x {hh,lh,hl}), 20 ds_read_b128, 8 DMA/wave.
__global__ __launch_bounds__(256) void k_dist_bf16(
    const unsigned short* __restrict__ Xh, const unsigned short* __restrict__ Xl,
    const unsigned short* __restrict__ Eh, const unsigned short* __restrict__ El,
    const float* __restrict__ EN, float2* __restrict__ cand) {
  __shared__ unsigned short sXh[BM * BK], sXl[BM * BK];
  __shared__ unsigned short sEh[BN * BK], sEl[BN * BK];
  __shared__ float sEN[BN];

  const int tid = threadIdx.x;
  const int lane = tid & 63;
  const int w = tid >> 6;          // wave id
  const int quad = lane >> 4;      // 0..3
  const int lx = lane & 15;
  const int rowBase = blockIdx.x * BM;
  const int colBase = blockIdx.y * BN;

  if (tid < BN) sEN[tid] = EN[colBase + tid];

  // DMA source mapping: 512 chunks/buffer, 2 wave-instrs per buffer
  int crow[2], cq[2];
#pragma unroll
  for (int i = 0; i < 2; ++i) {
    int c = i * 256 + tid;
    crow[i] = c >> 2;
    cq[i] = (c & 3) ^ ((crow[i] >> 1) & 3);
  }

  // frag LDS offsets (constant per lane): A chunk = quad of row; B likewise
  int aidx[2], bidx[8];
#pragma unroll
  for (int mt = 0; mt < 2; ++mt) {
    int r = w * 32 + mt * 16 + lx;
    aidx[mt] = chidx(r, quad);
  }
#pragma unroll
  for (int ct = 0; ct < 8; ++ct) {
    int n = ct * 16 + lx;
    bidx[ct] = chidx(n, quad);
  }

  f32x4 acc[2][8];
#pragma unroll
  for (int mt = 0; mt < 2; ++mt)
#pragma unroll
    for (int ct = 0; ct < 8; ++ct) acc[mt][ct] = (f32x4){0.f, 0.f, 0.f, 0.f};

  for (int kt = 0; kt < KD / BK; ++kt) {
    const int kb = kt * BK;
    __syncthreads();  // previous tile's readers done
#pragma unroll
    for (int i = 0; i < 2; ++i) {
      const int ldsOff = (i * 256 + w * 64) * 8;  // wave-uniform chunk base
      const size_t xo = (size_t)(rowBase + crow[i]) * KD + kb + cq[i] * 8;
      const size_t eo = (size_t)(colBase + crow[i]) * KD + kb + cq[i] * 8;
      dma16(Xh + xo, &sXh[ldsOff]);
      dma16(Xl + xo, &sXl[ldsOff]);
      dma16(Eh + eo, &sEh[ldsOff]);
      dma16(El + eo, &sEl[ldsOff]);
    }
    __syncthreads();  // compiler drains vmcnt before barrier

    bf16x8 Ah[2], Al[2];
#pragma unroll
    for (int mt = 0; mt < 2; ++mt) {
      Ah[mt] = *(const bf16x8*)&sXh[aidx[mt]];
      Al[mt] = *(const bf16x8*)&sXl[aidx[mt]];
    }
#pragma unroll
    for (int ct = 0; ct < 8; ++ct) {
      bf16x8 Bh = *(const bf16x8*)&sEh[bidx[ct]];
      bf16x8 Bl = *(const bf16x8*)&sEl[bidx[ct]];
#pragma unroll
      for (int mt = 0; mt < 2; ++mt) {
        acc[mt][ct] = __builtin_amdgcn_mfma_f32_16x16x32_bf16(Ah[mt], Bh, acc[mt][ct], 0, 0, 0);
        acc[mt][ct] = __builtin_amdgcn_mfma_f32_16x16x32_bf16(Al[mt], Bh, acc[mt][ct], 0, 0, 0);
        acc[mt][ct] = __builtin_amdgcn_mfma_f32_16x16x32_bf16(Ah[mt], Bl, acc[mt][ct], 0, 0, 0);
      }
    }
  }

  // epilogue: C/D layout col=lane&15, row=quad*4+reg (m89/m91).
  // Lane's cols: ct*16+lx; rows: w*32 + mt*16 + quad*4 + j.
  float en[8];
#pragma unroll
  for (int ct = 0; ct < 8; ++ct) en[ct] = sEN[ct * 16 + lx];

#pragma unroll
  for (int mt = 0; mt < 2; ++mt) {
#pragma unroll
    for (int j = 0; j < 4; ++j) {
      float a0 = 3.4e38f, a1 = 3.4e38f, a2 = 3.4e38f, a3 = 3.4e38f;
      int i0 = 0x7fffffff, i1 = i0, i2 = i0, i3 = i0;
#pragma unroll
      for (int ct = 0; ct < 8; ++ct) {
        float d = en[ct] - 2.0f * acc[mt][ct][j];
        int ix = colBase + ct * 16 + lx;
        if (d < a3) {
          if (d < a2) { a3 = a2; i3 = i2;
            if (d < a1) { a2 = a1; i2 = i1;
              if (d < a0) { a1 = a0; i1 = i0; a0 = d; i0 = ix; }
              else { a1 = d; i1 = ix; } }
            else { a2 = d; i2 = ix; } }
          else { a3 = d; i3 = ix; }
        }
      }
      // butterfly merge of sorted top-4 lists across the 16 lx lanes
#pragma unroll
      for (int off = 1; off < 16; off <<= 1) {
        float b0 = __shfl_xor(a0, off, 16), b1 = __shfl_xor(a1, off, 16);
        float b2 = __shfl_xor(a2, off, 16), b3 = __shfl_xor(a3, off, 16);
        int j0 = __shfl_xor(i0, off, 16), j1 = __shfl_xor(i1, off, 16);
        int j2 = __shfl_xor(i2, off, 16), j3 = __shfl_xor(i3, off, 16);
        if (dless(b3, j3, a0, i0)) { a0 = b3; i0 = j3; }
        if (dless(b2, j2, a1, i1)) { a1 = b2; i1 = j2; }
        if (dless(b1, j1, a2, i2)) { a2 = b1; i2 = j1; }
        if (dless(b0, j0, a3, i3)) { a3 = b0; i3 = j0; }
        if (dless(a2, i2, a0, i0)) { float t = a0; a0 = a2; a2 = t; int u = i0; i0 = i2; i2 = u; }
        if (dless(a3, i3, a1, i1)) { float t = a1; a1 = a3; a3 = t; int u = i1; i1 = i3; i3 = u; }
        if (dless(a1, i1, a0, i0)) { float t = a0; a0 = a1; a1 = t; int u = i0; i0 = i1; i1 = u; }
        if (dless(a3, i3, a2, i2)) { float t = a2; a2 = a3; a3 = t; int u = i2; i2 = i3; i3 = u; }
      }
      if (lx == 0) {
        int row = rowBase + w * 32 + mt * 16 + quad * 4 + j;
        float2* dst = cand + (size_t)row * (NBLK * 4) + blockIdx.y * 4;
        dst[0] = make_float2(a0, __int_as_float(i0));
        dst[1] = make_float2(a1, __int_as_float(i1));
        dst[2] = make_float2(a2, __int_as_float(i2));
        dst[3] = make_float2(a3, __int_as_float(i3));
      }
    }
  }
}

// ---------------------------------------------------------------------------
// Fallback (ws too small for splits): round-3 fp32 VALU kernel, unchanged.
__global__ __launch_bounds__(256) void k_dist_f32(const float* __restrict__ X,
                                                  const float* __restrict__ E,
                                                  const float* __restrict__ EN,
                                                  float2* __restrict__ cand) {
  __shared__ float sX[BM * BK];
  __shared__ float sE[BN * BK];
  __shared__ float sEN[BN];

  const int tid = threadIdx.x;
  const int tx = tid & 15, ty = tid >> 4;
  const int w = tid >> 6;
  const int rowBase = blockIdx.x * BM;
  const int colBase = blockIdx.y * BN;

  if (tid < BN) sEN[tid] = EN[colBase + tid];

  int drow[4], dkq[4];
#pragma unroll
  for (int i = 0; i < 4; ++i) {
    int q = i * 256 + tid;
    drow[i] = q >> 3;
    dkq[i] = (q & 7) ^ (drow[i] & 7);
  }

  float acc[8][8];
#pragma unroll
  for (int r = 0; r < 8; ++r)
#pragma unroll
    for (int c = 0; c < 8; ++c) acc[r][c] = 0.f;

  const int xsw = ty & 7;
  const int esw = tx & 7;

  for (int kt = 0; kt < KD / BK; ++kt) {
    const int kb = kt * BK;
    __syncthreads();
#pragma unroll
    for (int i = 0; i < 4; ++i) {
      float* ldst = sX + (i * 256 + w * 64) * 4;
      dma16(X + (size_t)(rowBase + drow[i]) * KD + kb + 4 * dkq[i], ldst);
    }
#pragma unroll
    for (int i = 0; i < 4; ++i) {
      float* ldst = sE + (i * 256 + w * 64) * 4;
      dma16(E + (size_t)(colBase + drow[i]) * KD + kb + 4 * dkq[i], ldst);
    }
    __syncthreads();
#pragma unroll
    for (int kq = 0; kq < 8; ++kq) {
      float4 xv[8];
#pragma unroll
      for (int r = 0; r < 8; ++r)
        xv[r] = *(const float4*)&sX[((ty + 16 * r) * 8 + (kq ^ xsw)) * 4];
#pragma unroll
      for (int c = 0; c < 8; ++c) {
        float4 ev = *(const float4*)&sE[((tx + 16 * c) * 8 + (kq ^ esw)) * 4];
#pragma unroll
        for (int r = 0; r < 8; ++r) {
          acc[r][c] += xv[r].x * ev.x;
          acc[r][c] += xv[r].y * ev.y;
          acc[r][c] += xv[r].z * ev.z;
          acc[r][c] += xv[r].w * ev.w;
        }
      }
    }
  }

  float en[8];
#pragma unroll
  for (int c = 0; c < 8; ++c) en[c] = sEN[tx + 16 * c];

#pragma unroll
  for (int r = 0; r < 8; ++r) {
    float a0 = 3.4e38f, a1 = 3.4e38f, a2 = 3.4e38f, a3 = 3.4e38f;
    int i0 = 0x7fffffff, i1 = i0, i2 = i0, i3 = i0;
#pragma unroll
    for (int c = 0; c < 8; ++c) {
      float d = en[c] - 2.0f * acc[r][c];
      int ix = colBase + tx + 16 * c;
      if (d < a3) {
        if (d < a2) { a3 = a2; i3 = i2;
          if (d < a1) { a2 = a1; i2 = i1;
            if (d < a0) { a1 = a0; i1 = i0; a0 = d; i0 = ix; }
            else { a1 = d; i1 = ix; } }
          else { a2 = d; i2 = ix; } }
        else { a3 = d; i3 = ix; }
      }
    }
#pragma unroll
    for (int off = 1; off < 16; off <<= 1) {
      float b0 = __shfl_xor(a0, off, 16), b1 = __shfl_xor(a1, off, 16);
      float b2 = __shfl_xor(a2, off, 16), b3 = __shfl_xor(a3, off, 16);
      int j0 = __shfl_xor(i0, off, 16), j1 = __shfl_xor(i1, off, 16);
      int j2 = __shfl_xor(i2, off, 16), j3 = __shfl_xor(i3, off, 16);
      if (dless(b3, j3, a0, i0)) { a0 = b3; i0 = j3; }
      if (dless(b2, j2, a1, i1)) { a1 = b2; i1 = j2; }
      if (dless(b1, j1, a2, i2)) { a2 = b1; i2 = j1; }
      if (dless(b0, j0, a3, i3)) { a3 = b0; i3 = j0; }
      if (dless(a2, i2, a0, i0)) { float t = a0; a0 = a2; a2 = t; int u = i0; i0 = i2; i2 = u; }
      if (dless(a3, i3, a1, i1)) { float t = a1; a1 = a3; a3 = t; int u = i1; i1 = i3; i3 = u; }
      if (dless(a1, i1, a0, i0)) { float t = a0; a0 = a1; a1 = t; int u = i0; i0 = i1; i1 = u; }
      if (dless(a3, i3, a2, i2)) { float t = a2; a2 = a3; a3 = t; int u = i2; i2 = i3; i3 = u; }
    }
    if (tx == 0) {
      float2* dst = cand + (size_t)(rowBase + ty + 16 * r) * (NBLK * 4) + blockIdx.y * 4;
      dst[0] = make_float2(a0, __int_as_float(i0));
      dst[1] = make_float2(a1, __int_as_float(i1));
      dst[2] = make_float2(a2, __int_as_float(i2));
      dst[3] = make_float2(a3, __int_as_float(i3));
    }
  }
}

// ---------------------------------------------------------------------------
// K1b: merge 64 candidates/row -> global top-8 indices (64-lane bitonic).
__global__ __launch_bounds__(256) void k_merge(const float2* __restrict__ cand,
                                               int* __restrict__ top8) {
  const int lane = threadIdx.x & 63;
  const int row = blockIdx.x * 4 + (threadIdx.x >> 6);
  float2 e = cand[(size_t)row * 64 + lane];
  float d = e.x;
  int ix = __float_as_int(e.y);
#pragma unroll
  for (int k = 2; k <= 64; k <<= 1) {
#pragma unroll
    for (int j = k >> 1; j > 0; j >>= 1) {
      float od = __shfl_xor(d, j, 64);
      int oi = __shfl_xor(ix, j, 64);
      bool dirUp = (lane & k) == 0;
      bool lower = (lane & j) == 0;
      bool pl = dless(od, oi, d, ix);
      bool take = (dirUp == lower) ? pl : !pl;
      if (take) { d = od; ix = oi; }
    }
  }
  if (lane < 8) top8[(size_t)row * 8 + lane] = ix;
}

// ---------------------------------------------------------------------------
// K2: fp64 refinement of 8 candidates/row, gather nearest, per-row SSEs.
__global__ __launch_bounds__(256) void k_refine(const float* __restrict__ X,
                                                const float* __restrict__ E,
                                                const int* __restrict__ top8,
                                                float* __restrict__ outF,
                                                double* __restrict__ rowS) {
  const int row = blockIdx.x;
  const int tid = threadIdx.x;
  __shared__ int sc[8];
  __shared__ double sp[8][4];
  __shared__ int sBest;
  if (tid < 8) sc[tid] = top8[(size_t)row * 8 + tid];
  __syncthreads();
  const float x0 = X[(size_t)row * KD + tid];
  const float x1 = X[(size_t)row * KD + tid + 256];
  double a[8];
#pragma unroll
  for (int c = 0; c < 8; ++c) {
    const float* e = E + (size_t)sc[c] * KD;
    double d0 = (double)e[tid] - (double)x0;
    double d1 = (double)e[tid + 256] - (double)x1;
    a[c] = d0 * d0 + d1 * d1;
  }
#pragma unroll
  for (int c = 0; c < 8; ++c)
#pragma unroll
    for (int off = 32; off; off >>= 1) a[c] += __shfl_down(a[c], off);
  const int w = tid >> 6, lane = tid & 63;
  if (lane == 0) {
#pragma unroll
    for (int c = 0; c < 8; ++c) sp[c][w] = a[c];
  }
  __syncthreads();
  if (tid == 0) {
    double d[8]; int id[8];
#pragma unroll
    for (int c = 0; c < 8; ++c) {
      d[c] = sp[c][0] + sp[c][1] + sp[c][2] + sp[c][3];
      id[c] = sc[c];
    }
    for (int i = 0; i < 8; ++i)
      for (int j = i + 1; j < 8; ++j)
        if (d[j] < d[i] || (d[j] == d[i] && id[j] < id[i])) {
          double dt = d[i]; d[i] = d[j]; d[j] = dt;
          int it = id[i]; id[i] = id[j]; id[j] = it;
        }
    rowS[2 * row] = d[0];      // SSE to nearest
    rowS[2 * row + 1] = d[2];  // SSE to third
    sBest = id[0];
  }
  __syncthreads();
  const float* e1 = E + (size_t)sBest * KD;
  outF[(size_t)row * KD + tid] = e1[tid];
  outF[(size_t)row * KD + tid + 256] = e1[tid + 256];
}

// ---------------------------------------------------------------------------
// K3: deterministic fp64 reduction over rows -> cp_score, k_loss
__global__ __launch_bounds__(256) void k_finalize(const double* __restrict__ rowS,
                                                  float* __restrict__ out) {
  const int tid = threadIdx.x;
  double a1 = 0.0, a3 = 0.0;
  for (int r = tid; r < RM; r += 256) { a1 += rowS[2 * r]; a3 += rowS[2 * r + 1]; }
#pragma unroll
  for (int off = 32; off; off >>= 1) {
    a1 += __shfl_down(a1, off);
    a3 += __shfl_down(a3, off);
  }
  __shared__ double s1[4], s3[4];
  const int w = tid >> 6, lane = tid & 63;
  if (lane == 0) { s1[w] = a1; s3[w] = a3; }
  __syncthreads();
  if (tid == 0) {
    double S1 = s1[0] + s1[1] + s1[2] + s1[3];
    double S3 = s3[0] + s3[1] + s3[2] + s3[3];
    out[0] = (float)(1.0 - sqrt(S1 / S3));   // cp_score
    out[1] = (float)(0.25 * S1 / NELEM);     // k_loss
  }
}

// ---------------------------------------------------------------------------
extern "C" void kernel_launch(void* const* d_in, const int* in_sizes, int n_in,
                              void* d_out, int out_size, void* d_ws, size_t ws_size,
                              hipStream_t stream) {
  const float* IP = (const float*)d_in[0];   // (256,51,512) fp32
  const float* EMB = (const float*)d_in[1];  // (2048,512) fp32
  float* out = (float*)d_out;

  // d_out tail doubles as candidate scratch (overwritten later by k_refine)
  float2* cand = (float2*)(out + 2);

  // ws layout (all 16B-aligned): EN | top8 | rowS | Xh | Xl | Eh | El
  char* ws = (char*)d_ws;
  size_t off = 16;
  float* EN = (float*)(ws + off);        off += NE * 4;                 // 8 KB
  int* top8 = (int*)(ws + off);          off += (size_t)RM * 8 * 4;     // 417 KB
  double* rowS = (double*)(ws + off);    off += (size_t)RM * 2 * 8;     // 209 KB
  unsigned short* Xh = (unsigned short*)(ws + off); off += (size_t)RM * KD * 2;
  unsigned short* Xl = (unsigned short*)(ws + off); off += (size_t)RM * KD * 2;
  unsigned short* Ehs = (unsigned short*)(ws + off); off += (size_t)NE * KD * 2;
  unsigned short* Els = (unsigned short*)(ws + off); off += (size_t)NE * KD * 2;
  const bool fast = ws_size >= off;      // ~30.1 MiB needed for split path

  hipLaunchKernelGGL(k_emb_norms, dim3(NE / 4), dim3(256), 0, stream, EMB, EN);
  if (fast) {
    hipLaunchKernelGGL(k_split, dim3(RM * KD / 1024), dim3(256), 0, stream,
                       IP, Xh, Xl, RM * KD / 4);
    hipLaunchKernelGGL(k_split, dim3(NE * KD / 1024), dim3(256), 0, stream,
                       EMB, Ehs, Els, NE * KD / 4);
    hipLaunchKernelGGL(k_dist_bf16, dim3(RM / BM, NBLK), dim3(256), 0, stream,
                       Xh, Xl, Ehs, Els, EN, cand);
  } else {
    hipLaunchKernelGGL(k_dist_f32, dim3(RM / BM, NBLK), dim3(256), 0, stream,
                       IP, EMB, EN, cand);
  }
  hipLaunchKernelGGL(k_merge, dim3(RM / 4), dim3(256), 0, stream, cand, top8);
  hipLaunchKernelGGL(k_refine, dim3(RM), dim3(256), 0, stream, IP, EMB, top8, out + 2, rowS);
  hipLaunchKernelGGL(k_finalize, dim3(1), dim3(256), 0, stream, rowS, out);
}

// Round 5
// 259.604 us; speedup vs baseline: 3.8580x; 1.3065x over previous
//
#include <hip/hip_runtime.h>
#include <hip/hip_bf16.h>
#include <math.h>

// Problem constants
#define RM 13056         // 256*17*3 rows of flat x
#define KD 512           // feature dim
#define NE 2048          // codebook entries
#define NELEM 6684672.0  // 256*51*512 elements for the mean

// dist kernel tiling
#define BM 128
#define BN 128
#define BK 32
#define NKT (KD / BK)    // 16 k-tiles
#define NBLK (NE / BN)   // 16 n-blocks

typedef __attribute__((ext_vector_type(8))) short bf16x8;
typedef __attribute__((ext_vector_type(4))) float f32x4;
typedef unsigned long long ull;

// async global->LDS, 16B per lane; lds base wave-uniform, HW appends lane*16 (m104)
__device__ __forceinline__ void dma16(const void* g, void* l) {
  __builtin_amdgcn_global_load_lds((const __attribute__((address_space(1))) void*)g,
                                   (__attribute__((address_space(3))) void*)l, 16, 0, 0);
}

// order-preserving (dist, idx) -> u64 key: ascending u64 == lexicographic (d, ix)
__device__ __forceinline__ ull packdi(float d, int ix) {
  unsigned u = __float_as_uint(d);
  u ^= (unsigned)((int)u >> 31) | 0x80000000u;
  return ((ull)u << 32) | (unsigned)ix;
}

// ---------------------------------------------------------------------------
// K_pre: split fp32 -> bf16 hi + residual lo, emitted in the k_dist DMA layout:
// chunk index o = (kt*rows + row)*4 + slot, slot = q ^ ((row>>1)&3), where the
// chunk holds elements src[row][kt*32 + q*8 .. +8]. Consecutive o = consecutive
// 16B in memory = exactly the order global_load_lds deposits into LDS.
__global__ __launch_bounds__(256) void k_split(const float* __restrict__ src,
                                               unsigned short* __restrict__ hi,
                                               unsigned short* __restrict__ lo,
                                               int rows) {
  int o = blockIdx.x * 256 + threadIdx.x;      // chunk id, total rows*64
  int t4 = o >> 2;
  int kt = t4 / rows;
  int row = t4 - kt * rows;
  int slot = o & 3;
  int q = slot ^ ((row >> 1) & 3);
  const float* s = src + (size_t)row * KD + kt * 32 + q * 8;
  float4 v0 = ((const float4*)s)[0];
  float4 v1 = ((const float4*)s)[1];
  float f[8] = {v0.x, v0.y, v0.z, v0.w, v1.x, v1.y, v1.z, v1.w};
  unsigned hh[4], ll[4];
#pragma unroll
  for (int j = 0; j < 4; ++j) {
    __hip_bfloat16 b0 = __float2bfloat16(f[2 * j]);
    __hip_bfloat16 b1 = __float2bfloat16(f[2 * j + 1]);
    __hip_bfloat16 c0 = __float2bfloat16(f[2 * j] - __bfloat162float(b0));
    __hip_bfloat16 c1 = __float2bfloat16(f[2 * j + 1] - __bfloat162float(b1));
    hh[j] = (unsigned)*(unsigned short*)&b0 | ((unsigned)*(unsigned short*)&b1 << 16);
    ll[j] = (unsigned)*(unsigned short*)&c0 | ((unsigned)*(unsigned short*)&c1 << 16);
  }
  ((uint4*)hi)[o] = make_uint4(hh[0], hh[1], hh[2], hh[3]);
  ((uint4*)lo)[o] = make_uint4(ll[0], ll[1], ll[2], ll[3]);
}

// ---------------------------------------------------------------------------
// K0: per-codeword squared norms  EN[n] = sum_k E[n][k]^2 (fp32)
__global__ __launch_bounds__(256) void k_emb_norms(const float* __restrict__ E,
                                                   float* __restrict__ EN) {
  int n = blockIdx.x * 4 + (threadIdx.x >> 6);
  int lane = threadIdx.x & 63;
  const float* e = E + (size_t)n * KD;
  float s = 0.f;
#pragma unroll
  for (int j = 0; j < 8; ++j) { float v = e[lane + 64 * j]; s += v * v; }
#pragma unroll
  for (int off = 32; off; off >>= 1) s += __shfl_down(s, off);
  if (lane == 0) EN[n] = s;
}

// ---------------------------------------------------------------------------
// LDS chunk addressing (ushort elem offset): chunk q of local row at slot
// q ^ ((row>>1)&3). Identical LDS image to round 4 (conflicts measured 0).
__device__ __forceinline__ int chidx(int row, int q) {
  return (row * 4 + (q ^ ((row >> 1) & 3))) * 8;
}

// K1: split-bf16 MFMA distance tile + per-row top-4 within this n-block.
// grid (102,16), block 256 = 4 waves. Per kt: 48 MFMA, 20 ds_read_b128,
// 8 contiguous-1KiB DMA per wave. Epilogue: per-thread top-4 insert + 4-round
// u64 min-extraction across the 16-lane group.
__global__ __launch_bounds__(256) void k_dist_bf16(
    const unsigned short* __restrict__ Xh, const unsigned short* __restrict__ Xl,
    const unsigned short* __restrict__ Eh, const unsigned short* __restrict__ El,
    const float* __restrict__ EN, ull* __restrict__ cand) {
  __shared__ unsigned short sXh[BM * BK], sXl[BM * BK];
  __shared__ unsigned short sEh[BN * BK], sEl[BN * BK];
  __shared__ float sEN[BN];

  const int tid = threadIdx.x;
  const int lane = tid & 63;
  const int w = tid >> 6;
  const int quad = lane >> 4;
  const int lx = lane & 15;
  const int rowBase = blockIdx.x * BM;
  const int colBase = blockIdx.y * BN;

  if (tid < BN) sEN[tid] = EN[colBase + tid];

  // frag LDS offsets (constant per lane)
  int aidx[2], bidx[8];
#pragma unroll
  for (int mt = 0; mt < 2; ++mt) aidx[mt] = chidx(w * 32 + mt * 16 + lx, quad);
#pragma unroll
  for (int ct = 0; ct < 8; ++ct) bidx[ct] = chidx(ct * 16 + lx, quad);

  f32x4 acc[2][8];
#pragma unroll
  for (int mt = 0; mt < 2; ++mt)
#pragma unroll
    for (int ct = 0; ct < 8; ++ct) acc[mt][ct] = (f32x4){0.f, 0.f, 0.f, 0.f};

  for (int kt = 0; kt < NKT; ++kt) {
    // contiguous tile bases in the transformed layout (chunk granularity)
    const size_t xbase = ((size_t)kt * RM + rowBase) * 4;
    const size_t ebase = ((size_t)kt * NE + colBase) * 4;
    __syncthreads();  // previous tile's readers done
#pragma unroll
    for (int i = 0; i < 2; ++i) {
      const int c = i * 256 + tid;                   // chunk within tile
      const int ldsOff = (i * 256 + w * 64) * 8;     // wave-uniform LDS base
      dma16(Xh + (xbase + c) * 8, &sXh[ldsOff]);
      dma16(Xl + (xbase + c) * 8, &sXl[ldsOff]);
      dma16(Eh + (ebase + c) * 8, &sEh[ldsOff]);
      dma16(El + (ebase + c) * 8, &sEl[ldsOff]);
    }
    __syncthreads();  // compiler drains vmcnt before barrier

    bf16x8 Ah[2], Al[2];
#pragma unroll
    for (int mt = 0; mt < 2; ++mt) {
      Ah[mt] = *(const bf16x8*)&sXh[aidx[mt]];
      Al[mt] = *(const bf16x8*)&sXl[aidx[mt]];
    }
#pragma unroll
    for (int ct = 0; ct < 8; ++ct) {
      bf16x8 Bh = *(const bf16x8*)&sEh[bidx[ct]];
      bf16x8 Bl = *(const bf16x8*)&sEl[bidx[ct]];
#pragma unroll
      for (int mt = 0; mt < 2; ++mt) {
        acc[mt][ct] = __builtin_amdgcn_mfma_f32_16x16x32_bf16(Ah[mt], Bh, acc[mt][ct], 0, 0, 0);
        acc[mt][ct] = __builtin_amdgcn_mfma_f32_16x16x32_bf16(Al[mt], Bh, acc[mt][ct], 0, 0, 0);
        acc[mt][ct] = __builtin_amdgcn_mfma_f32_16x16x32_bf16(Ah[mt], Bl, acc[mt][ct], 0, 0, 0);
      }
    }
  }

  // epilogue: C/D layout col=lane&15, row=quad*4+reg (m89/m91)
  float en[8];
#pragma unroll
  for (int ct = 0; ct < 8; ++ct) en[ct] = sEN[ct * 16 + lx];

#pragma unroll
  for (int mt = 0; mt < 2; ++mt) {
#pragma unroll
    for (int j = 0; j < 4; ++j) {
      float a0 = 3.4e38f, a1 = 3.4e38f, a2 = 3.4e38f, a3 = 3.4e38f;
      int i0 = 0x7fffffff, i1 = i0, i2 = i0, i3 = i0;
#pragma unroll
      for (int ct = 0; ct < 8; ++ct) {
        float d = en[ct] - 2.0f * acc[mt][ct][j];
        int ix = colBase + ct * 16 + lx;
        // ascending idx + strict < keeps the lower index on ties
        if (d < a3) {
          if (d < a2) { a3 = a2; i3 = i2;
            if (d < a1) { a2 = a1; i2 = i1;
              if (d < a0) { a1 = a0; i1 = i0; a0 = d; i0 = ix; }
              else { a1 = d; i1 = ix; } }
            else { a2 = d; i2 = ix; } }
          else { a3 = d; i3 = ix; }
        }
      }
      // 4-round min-extraction across the 16-lane group (keys unique per row)
      ull k0 = packdi(a0, i0), k1 = packdi(a1, i1);
      ull k2 = packdi(a2, i2), k3 = packdi(a3, i3);
      int pos = 0;
      ull res[4];
#pragma unroll
      for (int r = 0; r < 4; ++r) {
        ull h = pos == 0 ? k0 : pos == 1 ? k1 : pos == 2 ? k2 : pos == 3 ? k3 : ~0ull;
        ull m = h;
#pragma unroll
        for (int step = 1; step < 16; step <<= 1) {
          ull o = __shfl_xor(m, step, 16);
          m = o < m ? o : m;
        }
        res[r] = m;
        pos += (h == m) ? 1 : 0;
      }
      if (lx == 0) {
        int row = rowBase + w * 32 + mt * 16 + quad * 4 + j;
        ull* dst = cand + (size_t)row * (NBLK * 4) + blockIdx.y * 4;
        dst[0] = res[0]; dst[1] = res[1]; dst[2] = res[2]; dst[3] = res[3];
      }
    }
  }
}

// ---------------------------------------------------------------------------
// K1b: merge 64 candidates/row -> global top-8 indices (64-lane bitonic, u64).
__global__ __launch_bounds__(256) void k_merge(const ull* __restrict__ cand,
                                               int* __restrict__ top8) {
  const int lane = threadIdx.x & 63;
  const int row = blockIdx.x * 4 + (threadIdx.x >> 6);
  ull k = cand[(size_t)row * 64 + lane];
#pragma unroll
  for (int kk = 2; kk <= 64; kk <<= 1) {
#pragma unroll
    for (int j = kk >> 1; j > 0; j >>= 1) {
      ull o = __shfl_xor(k, j, 64);
      bool dirUp = (lane & kk) == 0;
      bool lower = (lane & j) == 0;
      bool pl = o < k;
      bool take = (dirUp == lower) ? pl : !pl;
      if (take) k = o;
    }
  }
  if (lane < 8) top8[(size_t)row * 8 + lane] = (int)(k & 0xffffffffull);
}

// ---------------------------------------------------------------------------
// K2: fp64 refinement, one wave per row (no LDS, no barriers). Gathers the 8
// candidate codewords, exact fp64 SSE, re-ranks, writes nearest row + SSEs.
__global__ __launch_bounds__(256) void k_refine(const float* __restrict__ X,
                                                const float* __restrict__ E,
                                                const int* __restrict__ top8,
                                                float* __restrict__ outF,
                                                double* __restrict__ rowS) {
  const int w = threadIdx.x >> 6, lane = threadIdx.x & 63;
  const int row = blockIdx.x * 4 + w;
  const float* xr = X + (size_t)row * KD;
  float4 x0 = *(const float4*)(xr + lane * 8);
  float4 x1 = *(const float4*)(xr + lane * 8 + 4);
  int ci[8];
#pragma unroll
  for (int c = 0; c < 8; ++c) ci[c] = top8[(size_t)row * 8 + c];
  double a[8];
#pragma unroll
  for (int c = 0; c < 8; ++c) {
    const float* er = E + (size_t)ci[c] * KD;
    float4 e0 = *(const float4*)(er + lane * 8);
    float4 e1 = *(const float4*)(er + lane * 8 + 4);
    double s = 0.0;
    double d0 = (double)e0.x - (double)x0.x; s += d0 * d0;
    double d1 = (double)e0.y - (double)x0.y; s += d1 * d1;
    double d2 = (double)e0.z - (double)x0.z; s += d2 * d2;
    double d3 = (double)e0.w - (double)x0.w; s += d3 * d3;
    double d4 = (double)e1.x - (double)x1.x; s += d4 * d4;
    double d5 = (double)e1.y - (double)x1.y; s += d5 * d5;
    double d6 = (double)e1.z - (double)x1.z; s += d6 * d6;
    double d7 = (double)e1.w - (double)x1.w; s += d7 * d7;
    a[c] = s;
  }
#pragma unroll
  for (int c = 0; c < 8; ++c)
#pragma unroll
    for (int off = 32; off; off >>= 1) a[c] += __shfl_down(a[c], off);
  int best = 0;
  if (lane == 0) {
    double d[8]; int id[8];
#pragma unroll
    for (int c = 0; c < 8; ++c) { d[c] = a[c]; id[c] = ci[c]; }
    for (int i = 0; i < 8; ++i)
      for (int j = i + 1; j < 8; ++j)
        if (d[j] < d[i] || (d[j] == d[i] && id[j] < id[i])) {
          double dt = d[i]; d[i] = d[j]; d[j] = dt;
          int it = id[i]; id[i] = id[j]; id[j] = it;
        }
    rowS[2 * row] = d[0];      // SSE to nearest
    rowS[2 * row + 1] = d[2];  // SSE to third
    best = id[0];
  }
  best = __shfl(best, 0);
  const float* er = E + (size_t)best * KD;
  *(float4*)(outF + (size_t)row * KD + lane * 8) = *(const float4*)(er + lane * 8);
  *(float4*)(outF + (size_t)row * KD + lane * 8 + 4) = *(const float4*)(er + lane * 8 + 4);
}

// ---------------------------------------------------------------------------
// K3: deterministic fp64 reduction over rows -> cp_score, k_loss
__global__ __launch_bounds__(256) void k_finalize(const double* __restrict__ rowS,
                                                  float* __restrict__ out) {
  const int tid = threadIdx.x;
  double a1 = 0.0, a3 = 0.0;
  for (int r = tid; r < RM; r += 256) { a1 += rowS[2 * r]; a3 += rowS[2 * r + 1]; }
#pragma unroll
  for (int off = 32; off; off >>= 1) {
    a1 += __shfl_down(a1, off);
    a3 += __shfl_down(a3, off);
  }
  __shared__ double s1[4], s3[4];
  const int w = tid >> 6, lane = tid & 63;
  if (lane == 0) { s1[w] = a1; s3[w] = a3; }
  __syncthreads();
  if (tid == 0) {
    double S1 = s1[0] + s1[1] + s1[2] + s1[3];
    double S3 = s3[0] + s3[1] + s3[2] + s3[3];
    out[0] = (float)(1.0 - sqrt(S1 / S3));   // cp_score
    out[1] = (float)(0.25 * S1 / NELEM);     // k_loss
  }
}

// ---------------------------------------------------------------------------
extern "C" void kernel_launch(void* const* d_in, const int* in_sizes, int n_in,
                              void* d_out, int out_size, void* d_ws, size_t ws_size,
                              hipStream_t stream) {
  const float* IP = (const float*)d_in[0];   // (256,51,512) fp32
  const float* EMB = (const float*)d_in[1];  // (2048,512) fp32
  float* out = (float*)d_out;

  // d_out tail doubles as candidate scratch (overwritten later by k_refine):
  // 13056 rows x 64 u64 = 6.68 MB <= out capacity 26.7 MB. (out+2 is 8B-aligned.)
  ull* cand = (ull*)(out + 2);

  // ws layout (16B-aligned): EN | top8 | rowS | Xh | Xl | Eh | El  (~30.1 MiB)
  char* ws = (char*)d_ws;
  size_t off = 16;
  float* EN = (float*)(ws + off);        off += NE * 4;
  int* top8 = (int*)(ws + off);          off += (size_t)RM * 8 * 4;
  double* rowS = (double*)(ws + off);    off += (size_t)RM * 2 * 8;
  unsigned short* Xh = (unsigned short*)(ws + off); off += (size_t)RM * KD * 2;
  unsigned short* Xl = (unsigned short*)(ws + off); off += (size_t)RM * KD * 2;
  unsigned short* Ehs = (unsigned short*)(ws + off); off += (size_t)NE * KD * 2;
  unsigned short* Els = (unsigned short*)(ws + off); off += (size_t)NE * KD * 2;

  hipLaunchKernelGGL(k_emb_norms, dim3(NE / 4), dim3(256), 0, stream, EMB, EN);
  hipLaunchKernelGGL(k_split, dim3(RM * 64 / 256), dim3(256), 0, stream, IP, Xh, Xl, RM);
  hipLaunchKernelGGL(k_split, dim3(NE * 64 / 256), dim3(256), 0, stream, EMB, Ehs, Els, NE);
  hipLaunchKernelGGL(k_dist_bf16, dim3(RM / BM, NBLK), dim3(256), 0, stream,
                     Xh, Xl, Ehs, Els, EN, cand);
  hipLaunchKernelGGL(k_merge, dim3(RM / 4), dim3(256), 0, stream, cand, top8);
  hipLaunchKernelGGL(k_refine, dim3(RM / 4), dim3(256), 0, stream, IP, EMB, top8, out + 2, rowS);
  hipLaunchKernelGGL(k_finalize, dim3(1), dim3(256), 0, stream, rowS, out);
}